// Round 2
// baseline (280.001 us; speedup 1.0000x reference)
//
#include <hip/hip_runtime.h>
#include <hip/hip_bf16.h>
#include <stdint.h>

using bf16 = __hip_bfloat16;
typedef __attribute__((ext_vector_type(8))) short bf16x8;   // 8 bf16 raw bits (4 VGPRs)
typedef __attribute__((ext_vector_type(4))) float f32x4;

__device__ __forceinline__ void async_load16(const void* g, void* l) {
    __builtin_amdgcn_global_load_lds(
        (__attribute__((address_space(1))) const void*)g,
        (__attribute__((address_space(3))) void*)l,
        16, 0, 0);
}

__global__ __launch_bounds__(256) void cvt_f32_bf16(const float* __restrict__ src,
                                                    bf16* __restrict__ dst, int n) {
    int i = (blockIdx.x * 256 + threadIdx.x) * 8;
    if (i + 8 > n) return;
    float4 f0 = *(const float4*)(src + i);
    float4 f1 = *(const float4*)(src + i + 4);
    union { bf16 h[8]; uint4 u; } o;
    o.h[0] = __float2bfloat16(f0.x); o.h[1] = __float2bfloat16(f0.y);
    o.h[2] = __float2bfloat16(f0.z); o.h[3] = __float2bfloat16(f0.w);
    o.h[4] = __float2bfloat16(f1.x); o.h[5] = __float2bfloat16(f1.y);
    o.h[6] = __float2bfloat16(f1.z); o.h[7] = __float2bfloat16(f1.w);
    *(uint4*)(dst + i) = o.u;
}

// Transposing convert: src fp32 [R x C] row-major -> dst bf16 [C x R] row-major.
__global__ __launch_bounds__(256) void cvt_t_f32_bf16(const float* __restrict__ src,
                                                      bf16* __restrict__ dst, int R, int C) {
    __shared__ bf16 tile[32][33];
    const int bx = blockIdx.x * 32;            // col base in src
    const int by = blockIdx.y * 32;            // row base in src
    const int tx = threadIdx.x & 31;
    const int ty4 = (threadIdx.x >> 5) * 4;
#pragma unroll
    for (int r = 0; r < 4; ++r)
        tile[ty4 + r][tx] = __float2bfloat16(src[(size_t)(by + ty4 + r) * C + bx + tx]);
    __syncthreads();
#pragma unroll
    for (int r = 0; r < 4; ++r)
        dst[(size_t)(bx + ty4 + r) * R + by + tx] = tile[tx][ty4 + r];
}

// C[M x N] = A[M x K] * B[N x K]^T, A/B bf16 row-major (K contiguous).
// EPI==0: store C as bf16 into Cb. EPI==1: Cf[idx] = Res[idx] + (*scale_ptr)*acc (fp32).
// Tile: 128x128, BK=32, 256 threads = 4 waves in 2x2, each wave 64x64 via 4x4 MFMA 16x16x32.
template<int EPI>
__global__ __launch_bounds__(256) void gemm_nt(
    const bf16* __restrict__ A, const bf16* __restrict__ B,
    bf16* __restrict__ Cb, float* __restrict__ Cf,
    const float* __restrict__ Res, const float* __restrict__ scale_ptr,
    int M, int N, int K)
{
    __shared__ __align__(16) bf16 As[128 * 32];
    __shared__ __align__(16) bf16 Bs[128 * 32];

    const int tid  = threadIdx.x;
    const int wave = tid >> 6;
    const int lane = tid & 63;
    const int wm = wave >> 1, wn = wave & 1;
    const size_t bm = (size_t)blockIdx.x * 128;
    const size_t bn = (size_t)blockIdx.y * 128;

    f32x4 acc[4][4];
#pragma unroll
    for (int i = 0; i < 4; ++i)
#pragma unroll
        for (int j = 0; j < 4; ++j)
            acc[i][j] = (f32x4){0.f, 0.f, 0.f, 0.f};

    const int srow = lane >> 2;
    const int scol = (lane & 3) * 8;

    for (int k0 = 0; k0 < K; k0 += 32) {
#pragma unroll
        for (int c = 0; c < 2; ++c) {
            const int rbase = c * 64 + wave * 16;          // wave-uniform
            async_load16(A + (bm + rbase + srow) * (size_t)K + k0 + scol, &As[rbase * 32]);
            async_load16(B + (bn + rbase + srow) * (size_t)K + k0 + scol, &Bs[rbase * 32]);
        }
        __syncthreads();

        bf16x8 af[4], bfr[4];
#pragma unroll
        for (int i = 0; i < 4; ++i)
            af[i] = *(const bf16x8*)&As[(wm * 64 + i * 16 + (lane & 15)) * 32 + (lane >> 4) * 8];
#pragma unroll
        for (int j = 0; j < 4; ++j)
            bfr[j] = *(const bf16x8*)&Bs[(wn * 64 + j * 16 + (lane & 15)) * 32 + (lane >> 4) * 8];
#pragma unroll
        for (int i = 0; i < 4; ++i)
#pragma unroll
            for (int j = 0; j < 4; ++j)
                acc[i][j] = __builtin_amdgcn_mfma_f32_16x16x32_bf16(af[i], bfr[j], acc[i][j], 0, 0, 0);
        __syncthreads();
    }

    // C/D layout: col = lane&15, row = (lane>>4)*4 + reg
    const int col_l = lane & 15;
    const int row_l = (lane >> 4) * 4;
    if (EPI == 0) {
#pragma unroll
        for (int i = 0; i < 4; ++i)
#pragma unroll
            for (int j = 0; j < 4; ++j)
#pragma unroll
                for (int r = 0; r < 4; ++r) {
                    size_t row = bm + wm * 64 + i * 16 + row_l + r;
                    size_t col = bn + wn * 64 + j * 16 + col_l;
                    Cb[row * (size_t)N + col] = __float2bfloat16(acc[i][j][r]);
                }
    } else {
        const float s = *scale_ptr;
#pragma unroll
        for (int i = 0; i < 4; ++i)
#pragma unroll
            for (int j = 0; j < 4; ++j)
#pragma unroll
                for (int r = 0; r < 4; ++r) {
                    size_t row = bm + wm * 64 + i * 16 + row_l + r;
                    size_t col = bn + wn * 64 + j * 16 + col_l;
                    size_t idx = row * (size_t)N + col;
                    Cf[idx] = Res[idx] + s * acc[i][j][r];
                }
    }
}

extern "C" void kernel_launch(void* const* d_in, const int* in_sizes, int n_in,
                              void* d_out, int out_size, void* d_ws, size_t ws_size,
                              hipStream_t stream) {
    // setup_inputs() order: hidden_states, w_down, w_up, w1, w2, residual_scale
    const float* hs     = (const float*)d_in[0];   // [8192, 2048]
    const float* w_down = (const float*)d_in[1];   // [512, 2048]
    const float* w_up   = (const float*)d_in[2];   // [2048, 512]
    const float* w1     = (const float*)d_in[3];   // [512, 512]
    const float* w2     = (const float*)d_in[4];   // [512, 512]
    const float* rs     = (const float*)d_in[5];   // scalar on device

    const int T = 8192, Q = 2048, H = 512;

    char* ws = (char*)d_ws;
    bf16* hs_b  = (bf16*)(ws + 0);          // 33,554,432
    bf16* wu_b  = (bf16*)(ws + 33554432);   //  2,097,152  Wup [2048x512]
    bf16* w2_b  = (bf16*)(ws + 35651584);   //    524,288  W2  [512x512]
    bf16* w1t_b = (bf16*)(ws + 36175872);   //    524,288  W1^T [512x512]
    bf16* wdt_b = (bf16*)(ws + 36700160);   //  2,097,152  Wd^T [2048x512]
    bf16* r1    = (bf16*)(ws + 38797312);   //    524,288  R1 = W2@W1 [512x512]
    bf16* r2t   = (bf16*)(ws + 39321600);   //  2,097,152  R2^T = (W2@W1@Wd)^T [2048x512]
    bf16* wall  = (bf16*)(ws + 41418752);   //  8,388,608  Wall = Wup@W2@W1@Wd [2048x2048]

    // Conversions
    cvt_f32_bf16<<<dim3((T * Q) / 2048), dim3(256), 0, stream>>>(hs, hs_b, T * Q);
    cvt_f32_bf16<<<dim3((Q * H) / 2048), dim3(256), 0, stream>>>(w_up, wu_b, Q * H);
    cvt_f32_bf16<<<dim3((H * H) / 2048), dim3(256), 0, stream>>>(w2, w2_b, H * H);
    cvt_t_f32_bf16<<<dim3(H / 32, H / 32), dim3(256), 0, stream>>>(w1, w1t_b, H, H);      // W1 [512x512] -> W1^T
    cvt_t_f32_bf16<<<dim3(Q / 32, H / 32), dim3(256), 0, stream>>>(w_down, wdt_b, H, Q);  // Wd [512x2048] -> Wd^T [2048x512]

    dim3 blk(256);
    // R1 = W2 @ W1 = NT(W2, W1^T): M=512, N=512, K=512
    gemm_nt<0><<<dim3(H / 128, H / 128), blk, 0, stream>>>(w2_b, w1t_b, r1, nullptr, nullptr, nullptr, H, H, H);
    // R2^T = NT(Wd^T, R1): M=2048, N=512, K=512   (== (R1@Wd)^T)
    gemm_nt<0><<<dim3(Q / 128, H / 128), blk, 0, stream>>>(wdt_b, r1, r2t, nullptr, nullptr, nullptr, Q, H, H);
    // Wall = Wup @ R2 = NT(Wup, R2^T): M=2048, N=2048, K=512
    gemm_nt<0><<<dim3(Q / 128, Q / 128), blk, 0, stream>>>(wu_b, r2t, wall, nullptr, nullptr, nullptr, Q, Q, H);
    // out = res + s * (hs @ Wall^T) = NT(hs_b, Wall): M=8192, N=2048, K=2048
    gemm_nt<1><<<dim3(T / 128, Q / 128), blk, 0, stream>>>(hs_b, wall, nullptr, (float*)d_out, hs, rs, T, Q, Q);
}

// Round 3
// 221.183 us; speedup vs baseline: 1.2659x; 1.2659x over previous
//
#include <hip/hip_runtime.h>
#include <hip/hip_bf16.h>
#include <stdint.h>

using bf16 = __hip_bfloat16;
typedef __attribute__((ext_vector_type(8))) short bf16x8;   // 8 bf16 raw bits (4 VGPRs)
typedef __attribute__((ext_vector_type(4))) float f32x4;

__device__ __forceinline__ void async_load16(const void* g, void* l) {
    __builtin_amdgcn_global_load_lds(
        (__attribute__((address_space(1))) const void*)g,
        (__attribute__((address_space(3))) void*)l,
        16, 0, 0);
}

__device__ __forceinline__ void cvt_block_2048(const float* __restrict__ src,
                                               bf16* __restrict__ dst, int relblk) {
    int i = (relblk * 256 + (int)threadIdx.x) * 8;
    float4 f0 = *(const float4*)(src + i);
    float4 f1 = *(const float4*)(src + i + 4);
    union { bf16 h[8]; uint4 u; } o;
    o.h[0] = __float2bfloat16(f0.x); o.h[1] = __float2bfloat16(f0.y);
    o.h[2] = __float2bfloat16(f0.z); o.h[3] = __float2bfloat16(f0.w);
    o.h[4] = __float2bfloat16(f1.x); o.h[5] = __float2bfloat16(f1.y);
    o.h[6] = __float2bfloat16(f1.z); o.h[7] = __float2bfloat16(f1.w);
    *(uint4*)(dst + i) = o.u;
}

// Three plain fp32->bf16 converts in one launch. nbK = element_count/2048.
__global__ __launch_bounds__(256) void cvt3(
    const float* __restrict__ s0, bf16* __restrict__ d0, int nb0,
    const float* __restrict__ s1, bf16* __restrict__ d1, int nb1,
    const float* __restrict__ s2, bf16* __restrict__ d2) {
    int b = blockIdx.x;
    if (b < nb0)            cvt_block_2048(s0, d0, b);
    else if (b < nb0 + nb1) cvt_block_2048(s1, d1, b - nb0);
    else                    cvt_block_2048(s2, d2, b - nb0 - nb1);
}

// Two transposing converts (src fp32 [R x C] -> dst bf16 [C x R]) in one launch.
__global__ __launch_bounds__(256) void cvt_t2(
    const float* __restrict__ s0, bf16* __restrict__ d0, int R0, int C0, int nb0,
    const float* __restrict__ s1, bf16* __restrict__ d1, int R1, int C1) {
    __shared__ bf16 tile[32][33];
    int b = blockIdx.x;
    const float* src; bf16* dst; int R, C, tx, ty;
    if (b < nb0) { src = s0; dst = d0; R = R0; C = C0; int ntx = C0 / 32; tx = b % ntx; ty = b / ntx; }
    else { b -= nb0; src = s1; dst = d1; R = R1; C = C1; int ntx = C1 / 32; tx = b % ntx; ty = b / ntx; }
    const int bx = tx * 32, by = ty * 32;
    const int lx = threadIdx.x & 31;
    const int ly4 = ((int)threadIdx.x >> 5) * 4;
#pragma unroll
    for (int r = 0; r < 4; ++r)
        tile[ly4 + r][lx] = __float2bfloat16(src[(size_t)(by + ly4 + r) * C + bx + lx]);
    __syncthreads();
#pragma unroll
    for (int r = 0; r < 4; ++r)
        dst[(size_t)(bx + ly4 + r) * R + by + lx] = tile[lx][ly4 + r];
}

// C[M x N] = A[M x K] * B[N x K]^T, bf16 row-major (K contiguous), BM=128 x BN tile.
// 4 waves in 2x2; wave tile 64 x (BN/2); 4 x (BN/32) grid of mfma 16x16x32.
// EPI==0: store bf16 to Cb.  EPI==1: Cf[idx] = Res[idx] + (*scale_ptr)*acc (fp32).
template<int BN, int EPI>
__global__ __launch_bounds__(256) void gemm_nt(
    const bf16* __restrict__ A, const bf16* __restrict__ B,
    bf16* __restrict__ Cb, float* __restrict__ Cf,
    const float* __restrict__ Res, const float* __restrict__ scale_ptr,
    int M, int N, int K)
{
    constexpr int BM = 128;
    constexpr int NJ = BN / 32;                 // mfma n-frags per wave
    __shared__ __align__(16) bf16 As[BM * 32];
    __shared__ __align__(16) bf16 Bs[BN * 32];

    const int tid  = threadIdx.x;
    const int wave = tid >> 6;
    const int lane = tid & 63;
    const int wm = wave >> 1, wn = wave & 1;
    const size_t bm = (size_t)blockIdx.x * BM;
    const size_t bn = (size_t)blockIdx.y * BN;

    f32x4 acc[4][NJ];
#pragma unroll
    for (int i = 0; i < 4; ++i)
#pragma unroll
        for (int j = 0; j < NJ; ++j)
            acc[i][j] = (f32x4){0.f, 0.f, 0.f, 0.f};

    const int srow = lane >> 2;                 // staging: 16 rows x 32 cols per call
    const int scol = (lane & 3) * 8;

    for (int k0 = 0; k0 < K; k0 += 32) {
#pragma unroll
        for (int c = 0; c < (BM + BN) / 64; ++c) {
            const int rbase = c * 64 + wave * 16;          // wave-uniform
            if (rbase < BM)
                async_load16(A + (bm + rbase + srow) * (size_t)K + k0 + scol, &As[rbase * 32]);
            else
                async_load16(B + (bn + (rbase - BM) + srow) * (size_t)K + k0 + scol,
                             &Bs[(rbase - BM) * 32]);
        }
        __syncthreads();

        bf16x8 af[4], bfr[NJ];
#pragma unroll
        for (int i = 0; i < 4; ++i)
            af[i] = *(const bf16x8*)&As[(wm * 64 + i * 16 + (lane & 15)) * 32 + (lane >> 4) * 8];
#pragma unroll
        for (int j = 0; j < NJ; ++j)
            bfr[j] = *(const bf16x8*)&Bs[(wn * (BN / 2) + j * 16 + (lane & 15)) * 32 + (lane >> 4) * 8];
#pragma unroll
        for (int i = 0; i < 4; ++i)
#pragma unroll
            for (int j = 0; j < NJ; ++j)
                acc[i][j] = __builtin_amdgcn_mfma_f32_16x16x32_bf16(af[i], bfr[j], acc[i][j], 0, 0, 0);
        __syncthreads();
    }

    // C/D layout: col = lane&15, row = (lane>>4)*4 + reg
    const int col_l = lane & 15;
    const int row_l = (lane >> 4) * 4;
    if (EPI == 0) {
#pragma unroll
        for (int i = 0; i < 4; ++i)
#pragma unroll
            for (int j = 0; j < NJ; ++j)
#pragma unroll
                for (int r = 0; r < 4; ++r) {
                    size_t row = bm + wm * 64 + i * 16 + row_l + r;
                    size_t col = bn + wn * (BN / 2) + j * 16 + col_l;
                    Cb[row * (size_t)N + col] = __float2bfloat16(acc[i][j][r]);
                }
    } else {
        const float s = *scale_ptr;
#pragma unroll
        for (int i = 0; i < 4; ++i)
#pragma unroll
            for (int j = 0; j < NJ; ++j)
#pragma unroll
                for (int r = 0; r < 4; ++r) {
                    size_t row = bm + wm * 64 + i * 16 + row_l + r;
                    size_t col = bn + wn * (BN / 2) + j * 16 + col_l;
                    size_t idx = row * (size_t)N + col;
                    Cf[idx] = Res[idx] + s * acc[i][j][r];
                }
    }
}

extern "C" void kernel_launch(void* const* d_in, const int* in_sizes, int n_in,
                              void* d_out, int out_size, void* d_ws, size_t ws_size,
                              hipStream_t stream) {
    // setup_inputs() order: hidden_states, w_down, w_up, w1, w2, residual_scale
    const float* hs     = (const float*)d_in[0];   // [8192, 2048]
    const float* w_down = (const float*)d_in[1];   // [512, 2048]
    const float* w_up   = (const float*)d_in[2];   // [2048, 512]
    const float* w1     = (const float*)d_in[3];   // [512, 512]
    const float* w2     = (const float*)d_in[4];   // [512, 512]
    const float* rs     = (const float*)d_in[5];   // scalar on device

    const int T = 8192, Q = 2048, H = 512;

    char* ws = (char*)d_ws;
    bf16* hs_b  = (bf16*)(ws + 0);          // 33,554,432  hs bf16 [8192x2048]
    bf16* x_b   = (bf16*)(ws + 33554432);   //  8,388,608  x [8192x512]
    bf16* w1_b  = (bf16*)(ws + 41943040);   //    524,288  W1 [512x512]
    bf16* wu_b  = (bf16*)(ws + 42467328);   //  2,097,152  Wup [2048x512]
    bf16* wdt_b = (bf16*)(ws + 44564480);   //  2,097,152  Wd^T [2048x512]
    bf16* w2t_b = (bf16*)(ws + 46661632);   //    524,288  W2^T [512x512]
    bf16* Rm    = (bf16*)(ws + 47185920);   //  2,097,152  R = W1*Wd [512x2048]
    bf16* Um    = (bf16*)(ws + 49283072);   //  2,097,152  U = Wup*W2 [2048x512]  (end 51,380,224)

    // 1) plain converts: hs (8192 blks), W1 (128 blks), Wup (512 blks)
    cvt3<<<dim3(8192 + 128 + 512), dim3(256), 0, stream>>>(hs, hs_b, 8192, w1, w1_b, 128, w_up, wu_b);
    // 2) transposing converts: Wd [512x2048] -> Wd^T (1024 tiles), W2 [512x512] -> W2^T (256 tiles)
    cvt_t2<<<dim3(1024 + 256), dim3(256), 0, stream>>>(w_down, wdt_b, H, Q, 1024, w2, w2t_b, H, H);

    dim3 blk(256);
    // 3) R = W1 * Wd = NT(W1, Wd^T): M=512, N=2048, K=512, BN=64 -> grid (4,32)
    gemm_nt<64, 0><<<dim3(H / 128, Q / 64), blk, 0, stream>>>(w1_b, wdt_b, Rm, nullptr, nullptr, nullptr, H, Q, H);
    // 4) U = Wup * W2 = NT(Wup, W2^T): M=2048, N=512, K=512, BN=64 -> grid (16,8)
    gemm_nt<64, 0><<<dim3(Q / 128, H / 64), blk, 0, stream>>>(wu_b, w2t_b, Um, nullptr, nullptr, nullptr, Q, H, H);
    // 5) x = hs * R^T = NT(hs_b, R): M=8192, N=512, K=2048, BN=64 -> grid (64,8)
    gemm_nt<64, 0><<<dim3(T / 128, H / 64), blk, 0, stream>>>(hs_b, Rm, x_b, nullptr, nullptr, nullptr, T, H, Q);
    // 6) out = res + s*(x * U^T) = NT(x_b, U): M=8192, N=2048, K=512, BN=128 -> grid (64,16)
    gemm_nt<128, 1><<<dim3(T / 128, Q / 128), blk, 0, stream>>>(x_b, Um, nullptr, (float*)d_out, hs, rs, T, Q, H);
}